// Round 2
// baseline (167.723 us; speedup 1.0000x reference)
//
#include <hip/hip_runtime.h>

#define BATCH   131072
#define NB      32          // N_BLOCKS
#define DIM     128         // 2*NB + M_REAL
#define DT      0.01f
#define THREADS_PER_ROW 8   // each thread: 4 complex pairs + 8 real cols

__global__ __launch_bounds__(256) void
koopman_kernel(const float4* __restrict__ x4,
               const float4* __restrict__ L4,
               float4* __restrict__ out4)
{
    int t   = blockIdx.x * blockDim.x + threadIdx.x;
    int row = t >> 3;           // t / 8
    int j   = t & 7;            // 0..7
    int base = row * (DIM / 4); // 32 float4 per row

    // ---- issue all 8 loads up front (independent, all dwordx4) ----
    float4 xa  = x4[base + 2 * j];          // complex cols 8j..8j+3
    float4 xb  = x4[base + 2 * j + 1];      // complex cols 8j+4..8j+7
    float4 mu  = L4[base + j];              // mu  cols 4j..4j+3
    float4 om  = L4[base + 8 + j];          // om  cols 32+4j..32+4j+3
    float4 xr0 = x4[base + 16 + 2 * j];     // real cols 64+8j..+3
    float4 xr1 = x4[base + 17 + 2 * j];     // real cols 64+8j+4..+7
    float4 l0  = L4[base + 16 + 2 * j];     // lam, same cols as xr0
    float4 l1  = L4[base + 17 + 2 * j];     // lam, same cols as xr1

    // ---- complex half: pair k uses mu[k], om[k] ----
    float e0 = __expf(mu.x * DT), e1 = __expf(mu.y * DT);
    float e2 = __expf(mu.z * DT), e3 = __expf(mu.w * DT);
    float s0, c0, s1, c1, s2, c2, s3, c3;
    __sincosf(om.x * DT, &s0, &c0);
    __sincosf(om.y * DT, &s1, &c1);
    __sincosf(om.z * DT, &s2, &c2);
    __sincosf(om.w * DT, &s3, &c3);

    float4 oa, ob;
    oa.x = e0 * (c0 * xa.x - s0 * xa.y);
    oa.y = e0 * (s0 * xa.x + c0 * xa.y);
    oa.z = e1 * (c1 * xa.z - s1 * xa.w);
    oa.w = e1 * (s1 * xa.z + c1 * xa.w);
    ob.x = e2 * (c2 * xb.x - s2 * xb.y);
    ob.y = e2 * (s2 * xb.x + c2 * xb.y);
    ob.z = e3 * (c3 * xb.z - s3 * xb.w);
    ob.w = e3 * (s3 * xb.z + c3 * xb.w);

    // ---- real half ----
    float4 or0, or1;
    or0.x = __expf(l0.x * DT) * xr0.x;
    or0.y = __expf(l0.y * DT) * xr0.y;
    or0.z = __expf(l0.z * DT) * xr0.z;
    or0.w = __expf(l0.w * DT) * xr0.w;
    or1.x = __expf(l1.x * DT) * xr1.x;
    or1.y = __expf(l1.y * DT) * xr1.y;
    or1.z = __expf(l1.z * DT) * xr1.z;
    or1.w = __expf(l1.w * DT) * xr1.w;

    // ---- 4 independent dwordx4 stores ----
    out4[base + 2 * j]      = oa;
    out4[base + 2 * j + 1]  = ob;
    out4[base + 16 + 2 * j] = or0;
    out4[base + 17 + 2 * j] = or1;
}

extern "C" void kernel_launch(void* const* d_in, const int* in_sizes, int n_in,
                              void* d_out, int out_size, void* d_ws, size_t ws_size,
                              hipStream_t stream)
{
    const float4* x4 = (const float4*)d_in[0];
    const float4* L4 = (const float4*)d_in[1];
    float4* out4     = (float4*)d_out;

    const int total_threads = BATCH * THREADS_PER_ROW;  // 1,048,576
    const int block = 256;
    const int grid  = total_threads / block;            // 4096

    koopman_kernel<<<grid, block, 0, stream>>>(x4, L4, out4);
}

// Round 4
// 156.383 us; speedup vs baseline: 1.0725x; 1.0725x over previous
//
#include <hip/hip_runtime.h>

#define BATCH   131072
#define DT      0.01f

// ext_vector types so __builtin_nontemporal_load/store accept them
using f4 = __attribute__((ext_vector_type(4))) float;
using f2 = __attribute__((ext_vector_type(2))) float;

// Mapping: 16 threads per row. Thread j (0..15) handles:
//   - complex float4 j    (x cols 4j..4j+3 = pairs 2j, 2j+1)
//   - real    float4 16+j (x cols 64+4j..64+4j+3)
// Lambda row layout: mu = cols 0..31, omega = cols 32..63, lam = cols 64..127.
__global__ __launch_bounds__(256) void
koopman_kernel(const f4* __restrict__ x4,
               const float* __restrict__ L,
               f4* __restrict__ out4)
{
    int t    = blockIdx.x * blockDim.x + threadIdx.x;   // [0, BATCH*16)
    int row  = t >> 4;
    int j    = t & 15;
    int base = row * 32;                                 // float4 index of row start
    const float* Lr = L + (size_t)row * 128;

    // ---- all loads nontemporal, issued up front ----
    f4 xc  = __builtin_nontemporal_load(x4 + base + j);          // complex half
    f4 xr  = __builtin_nontemporal_load(x4 + base + 16 + j);     // real half
    f2 mu  = __builtin_nontemporal_load((const f2*)(Lr + 2 * j));        // mu[2j], mu[2j+1]
    f2 om  = __builtin_nontemporal_load((const f2*)(Lr + 32 + 2 * j));   // om[2j], om[2j+1]  (cols 32..63!)
    f4 lam = __builtin_nontemporal_load((const f4*)(Lr + 64 + 4 * j));   // lam cols 64+4j..

    // ---- complex: pair k rotated by omega*dt, scaled by exp(mu*dt) ----
    float e0 = __expf(mu.x * DT);
    float e1 = __expf(mu.y * DT);
    float s0, c0, s1, c1;
    __sincosf(om.x * DT, &s0, &c0);
    __sincosf(om.y * DT, &s1, &c1);

    f4 oc;
    oc.x = e0 * (c0 * xc.x - s0 * xc.y);
    oc.y = e0 * (s0 * xc.x + c0 * xc.y);
    oc.z = e1 * (c1 * xc.z - s1 * xc.w);
    oc.w = e1 * (s1 * xc.z + c1 * xc.w);

    // ---- real ----
    f4 orr;
    orr.x = __expf(lam.x * DT) * xr.x;
    orr.y = __expf(lam.y * DT) * xr.y;
    orr.z = __expf(lam.z * DT) * xr.z;
    orr.w = __expf(lam.w * DT) * xr.w;

    // ---- nontemporal stores ----
    __builtin_nontemporal_store(oc,  out4 + base + j);
    __builtin_nontemporal_store(orr, out4 + base + 16 + j);
}

extern "C" void kernel_launch(void* const* d_in, const int* in_sizes, int n_in,
                              void* d_out, int out_size, void* d_ws, size_t ws_size,
                              hipStream_t stream)
{
    const f4* x4    = (const f4*)d_in[0];
    const float* L  = (const float*)d_in[1];
    f4* out4        = (f4*)d_out;

    const int total_threads = BATCH * 16;    // 2,097,152
    const int block = 256;
    const int grid  = total_threads / block; // 8192

    koopman_kernel<<<grid, block, 0, stream>>>(x4, L, out4);
}